// Round 3
// baseline (444.018 us; speedup 1.0000x reference)
//
#include <hip/hip_runtime.h>
#include <stdint.h>

#define IMG_H 256
#define IMG_W 256
#define ROWS_PER_WAVE 32          // output rows per wave
#define STRIPS 8                  // IMG_H / ROWS_PER_WAVE
#define N_IMG 1024                // 16 batch * 64 channels
#define WAVES_PER_BLOCK 4

typedef float vfloat4 __attribute__((ext_vector_type(4)));  // clang-native for nontemporal builtin

__device__ __forceinline__ float4 fmax4(const float4 a, const float4 b) {
    return make_float4(fmaxf(a.x, b.x), fmaxf(a.y, b.y), fmaxf(a.z, b.z), fmaxf(a.w, b.w));
}

// Fused hex maxpool, register-streaming v2: no LDS, no barriers.
// One wave spans the full 256-col row (64 lanes x float4). Rolling 5-row
// window + 4-row prefetch group (4 KiB in flight per wave steady-state,
// 9 KiB at prime). Non-temporal stores keep the read-only input resident
// in L3 (input 268 MB ~ L3 256 MB; output is never re-read).
// OOB rows/cols -> 0.0 (matches jnp.pad).
// w even: col w rows h-2..h+2 ; cols w+-1 rows h-2..h+1 ; cols w+-2 rows h-1..h+1
// w odd : col w rows h-2..h+2 ; cols w+-1 rows h-1..h+2 ; cols w+-2 rows h-1..h+1
__global__ __launch_bounds__(256, 4) void hex_maxpool_stream(const float* __restrict__ in,
                                                             float* __restrict__ out) {
    const int lane  = threadIdx.x & 63;
    const int wave  = threadIdx.x >> 6;
    const int W     = blockIdx.x * WAVES_PER_BLOCK + wave;   // global wave id
    const int img   = W >> 3;                                // 8 strips per image
    const int strip = W & 7;
    const int S     = strip * ROWS_PER_WAVE;                 // first output row

    const float* p = in  + (size_t)img * (IMG_H * IMG_W) + lane * 4;
    float*       q = out + (size_t)img * (IMG_H * IMG_W) + lane * 4;

    auto loadrow = [&](int g) -> float4 {
        if ((unsigned)g < (unsigned)IMG_H)                   // wave-uniform branch
            return *reinterpret_cast<const float4*>(p + (size_t)g * IMG_W);
        return make_float4(0.f, 0.f, 0.f, 0.f);
    };
    auto storerow = [&](int g, const float4 v) {
        vfloat4 nv;
        nv.x = v.x; nv.y = v.y; nv.z = v.z; nv.w = v.w;
        __builtin_nontemporal_store(nv, reinterpret_cast<vfloat4*>(q + (size_t)g * IMG_W));
    };

    // Verified-correct hex window reduction (identical math to prior versions).
    auto hexrow = [&](const float4 w0, const float4 w1, const float4 w2,
                      const float4 w3, const float4 w4) -> float4 {
        const float4 m3 = fmax4(fmax4(w1, w2), w3); // rows h-1..h+1
        const float4 bu = fmax4(m3, w0);            // rows h-2..h+1
        const float4 bd = fmax4(m3, w4);            // rows h-1..h+2
        const float4 a5 = fmax4(bu, w4);            // rows h-2..h+2

        float Lbuw = __shfl_up(bu.w, 1);
        float Lm3z = __shfl_up(m3.z, 1);
        float Lm3w = __shfl_up(m3.w, 1);
        float Rbdx = __shfl_down(bd.x, 1);
        float Rm3x = __shfl_down(m3.x, 1);
        float Rm3y = __shfl_down(m3.y, 1);
        if (lane == 0)  { Lbuw = 0.f; Lm3z = 0.f; Lm3w = 0.f; }  // cols -1,-2 pad(0)
        if (lane == 63) { Rbdx = 0.f; Rm3x = 0.f; Rm3y = 0.f; }  // cols 256,257 pad(0)

        float4 o;
        o.x = fmaxf(fmaxf(fmaxf(a5.x, Lbuw), bu.y), fmaxf(Lm3z, m3.z)); // even col
        o.y = fmaxf(fmaxf(fmaxf(a5.y, bd.x), bd.z), fmaxf(Lm3w, m3.w)); // odd col
        o.z = fmaxf(fmaxf(fmaxf(a5.z, bu.y), bu.w), fmaxf(m3.x, Rm3x)); // even col
        o.w = fmaxf(fmaxf(fmaxf(a5.w, bd.z), Rbdx), fmaxf(m3.y, Rm3y)); // odd col
        return o;
    };

    // Prime: window rows S-2..S+2 plus prefetch group rows S+3..S+6
    // (9 loads back-to-back = 9 KiB in flight before first use).
    float4 r0 = loadrow(S - 2);
    float4 r1 = loadrow(S - 1);
    float4 r2 = loadrow(S);
    float4 r3 = loadrow(S + 1);
    float4 r4 = loadrow(S + 2);
    float4 p0 = loadrow(S + 3);
    float4 p1 = loadrow(S + 4);
    float4 p2 = loadrow(S + 5);
    float4 p3 = loadrow(S + 6);

    // Main: 7 groups of 4 rows, each prefetching the next 4 rows before
    // computing (load-to-use distance = 4 row-computations + TLP).
#pragma unroll
    for (int k = 0; k < ROWS_PER_WAVE - 4; k += 4) {
        const float4 n0 = loadrow(S + 7 + k);
        const float4 n1 = loadrow(S + 8 + k);
        const float4 n2 = loadrow(S + 9 + k);
        const float4 n3 = loadrow(S + 10 + k);

        storerow(S + k,     hexrow(r0, r1, r2, r3, r4));
        storerow(S + k + 1, hexrow(r1, r2, r3, r4, p0));
        storerow(S + k + 2, hexrow(r2, r3, r4, p0, p1));
        storerow(S + k + 3, hexrow(r3, r4, p0, p1, p2));

        r0 = r4; r1 = p0; r2 = p1; r3 = p2; r4 = p3;
        p0 = n0; p1 = n1; p2 = n2; p3 = n3;
    }

    // Final group (k = 28): no prefetch. Window r0..r4 = rows S+26..S+30,
    // p0..p2 = rows S+31..S+33.
    storerow(S + 28, hexrow(r0, r1, r2, r3, r4));
    storerow(S + 29, hexrow(r1, r2, r3, r4, p0));
    storerow(S + 30, hexrow(r2, r3, r4, p0, p1));
    storerow(S + 31, hexrow(r3, r4, p0, p1, p2));
}

extern "C" void kernel_launch(void* const* d_in, const int* in_sizes, int n_in,
                              void* d_out, int out_size, void* d_ws, size_t ws_size,
                              hipStream_t stream) {
    (void)in_sizes; (void)n_in; (void)d_ws; (void)ws_size; (void)out_size;
    const float* in = (const float*)d_in[0];
    float* out = (float*)d_out;
    // 1024 images * 8 strips / 4 waves per block = 2048 blocks of 256 threads
    hex_maxpool_stream<<<(N_IMG * STRIPS) / WAVES_PER_BLOCK, 256, 0, stream>>>(in, out);
}